// Round 5
// baseline (235.921 us; speedup 1.0000x reference)
//
#include <hip/hip_runtime.h>

#define NN 50000
#define EE 800000
#define SCAN_BLOCKS 49  // 49*1024 >= 50000

typedef __attribute__((ext_vector_type(4))) float f32x4;
typedef __attribute__((ext_vector_type(8))) short bf16x8;
typedef unsigned int u32;
#define GLOBAL_AS __attribute__((address_space(1)))
#define LDS_AS __attribute__((address_space(3)))

static __device__ __forceinline__ unsigned short f2bf(float f) {
  unsigned int u = __float_as_uint(f);
  u += 0x7FFFu + ((u >> 16) & 1u);
  return (unsigned short)(u >> 16);
}
static __device__ __forceinline__ float bfl(unsigned int u) { return __uint_as_float(u << 16); }
static __device__ __forceinline__ float bfh(unsigned int u) { return __uint_as_float(u & 0xFFFF0000u); }

// ---- fused prep: conv x->bf16 | conv W->bf16 | init counts | att*0.4 ----
__global__ void k_prep(const float4* __restrict__ x4,
                       const float4* __restrict__ Wl, const float4* __restrict__ Wr,
                       const float4* __restrict__ Ws, const float* __restrict__ att,
                       uint2* __restrict__ xb2, uint2* __restrict__ wb2,
                       int* __restrict__ counts, float* __restrict__ att04) {
  int b = blockIdx.x;
  if (b < 12500) {
    int i = b * 256 + threadIdx.x;  // < 3200000 exactly
    float4 v = x4[i];
    uint2 o;
    o.x = (unsigned)f2bf(v.x) | ((unsigned)f2bf(v.y) << 16);
    o.y = (unsigned)f2bf(v.z) | ((unsigned)f2bf(v.w) << 16);
    xb2[i] = o;
  } else if (b < 12692) {
    int i = (b - 12500) * 256 + threadIdx.x;  // over 49152
    if (i < 49152) {
      int which = i >> 14;
      int idx = i & 16383;
      const float4* W = (which == 0) ? Wl : (which == 1) ? Wr : Ws;
      float4 v = W[idx];
      uint2 o;
      o.x = (unsigned)f2bf(v.x) | ((unsigned)f2bf(v.y) << 16);
      o.y = (unsigned)f2bf(v.z) | ((unsigned)f2bf(v.w) << 16);
      wb2[i] = o;
    }
  } else if (b < 12888) {
    int i = (b - 12692) * 256 + threadIdx.x;
    if (i < NN) counts[i] = 1;  // self-loop
  } else {
    att04[threadIdx.x] = 0.4f * att[threadIdx.x];  // 256 values
  }
}

// ---- GEMM: cols 0-255 -> xlb (bf16 [N][256]), cols 256-767 -> zb (bf16 [N][512]) ----
// Staging via global_load_lds: linear LDS dest, XOR-swizzle applied to the
// GLOBAL source address (rule #21); reads use the same swizzle.
__global__ __launch_bounds__(256) void k_gemm(const unsigned short* __restrict__ xb,
                                              const unsigned short* __restrict__ wb,
                                              unsigned short* __restrict__ xlb,
                                              unsigned short* __restrict__ zb) {
  __shared__ alignas(16) unsigned short As[128 * 64];
  __shared__ alignas(16) unsigned short Bs[128 * 64];
  const int tid = threadIdx.x;
  const int lane = tid & 63;
  const int wave = tid >> 6;
  const int wr = wave >> 1, wc = wave & 1;
  const int rbase = blockIdx.x * 128;
  const int cbase = blockIdx.y * 128;
  const int rl = lane & 15;
  const int q = lane >> 4;

  f32x4 acc[4][4];
#pragma unroll
  for (int a = 0; a < 4; ++a)
#pragma unroll
    for (int b = 0; b < 4; ++b) acc[a][b] = (f32x4){0.f, 0.f, 0.f, 0.f};

  for (int kt = 0; kt < 256; kt += 64) {
#pragma unroll
    for (int i = 0; i < 4; ++i) {
      int c = tid + i * 256;            // chunk id: 1024 chunks of 16B per buffer
      int row = c >> 3, kcx = c & 7;    // kcx = physical (linear LDS) slot
      int kc = kcx ^ (row & 7);         // logical k-chunk that lives in slot kcx
      int gr = rbase + row; if (gr > NN - 1) gr = NN - 1;
      int ldsoff = i * 4096 + wave * 1024;  // wave-uniform byte base
      __builtin_amdgcn_global_load_lds(
          (const GLOBAL_AS u32*)(xb + (size_t)gr * 256 + kt + kc * 8),
          (LDS_AS u32*)((LDS_AS char*)As + ldsoff), 16, 0, 0);
      __builtin_amdgcn_global_load_lds(
          (const GLOBAL_AS u32*)(wb + (size_t)(cbase + row) * 256 + kt + kc * 8),
          (LDS_AS u32*)((LDS_AS char*)Bs + ldsoff), 16, 0, 0);
    }
    __syncthreads();
#pragma unroll
    for (int ks = 0; ks < 2; ++ks) {
      bf16x8 af[4], bf[4];
      int kc = ks * 4 + q;
#pragma unroll
      for (int t = 0; t < 4; ++t) {
        int ra = wr * 64 + t * 16 + rl;
        af[t] = *(const bf16x8*)((const char*)As + ra * 128 + ((kc << 4) ^ ((ra & 7) << 4)));
        int rb = wc * 64 + t * 16 + rl;
        bf[t] = *(const bf16x8*)((const char*)Bs + rb * 128 + ((kc << 4) ^ ((rb & 7) << 4)));
      }
#pragma unroll
      for (int a = 0; a < 4; ++a)
#pragma unroll
        for (int b = 0; b < 4; ++b)
          acc[a][b] = __builtin_amdgcn_mfma_f32_16x16x32_bf16(af[a], bf[b], acc[a][b], 0, 0, 0);
    }
    __syncthreads();
  }
  const bool isxl = (cbase < 256);
#pragma unroll
  for (int a = 0; a < 4; ++a) {
#pragma unroll
    for (int j = 0; j < 4; ++j) {
      int row = rbase + wr * 64 + a * 16 + q * 4 + j;
      if (row < NN) {
#pragma unroll
        for (int b = 0; b < 4; ++b) {
          int col = cbase + wc * 64 + b * 16 + rl;
          if (isxl)
            xlb[(size_t)row * 256 + col] = f2bf(acc[a][b][j]);
          else
            zb[(size_t)row * 512 + (col - 256)] = f2bf(acc[a][b][j]);
        }
      }
    }
  }
}

// ---- dl6[j][h] = 1.5 * (att04 . xl_j,h)  ( = 0.6 * att . xl ) ----
__global__ __launch_bounds__(256) void k_dots(const uint2* __restrict__ xl2,
                                              const float* __restrict__ att04,
                                              float* __restrict__ dl6) {
  int node = blockIdx.x * 4 + (threadIdx.x >> 6);
  if (node >= NN) return;
  int lane = threadIdx.x & 63;
  uint2 v = xl2[(size_t)node * 64 + lane];
  const float4 av = *(const float4*)(att04 + lane * 4);
  float p = av.x * bfl(v.x) + av.y * bfh(v.x) + av.z * bfl(v.y) + av.w * bfh(v.y);
  p += __shfl_xor(p, 1);
  p += __shfl_xor(p, 2);
  p += __shfl_xor(p, 4);
  if ((lane & 7) == 0) dl6[(size_t)node * 8 + (lane >> 3)] = 1.5f * p;
}

__global__ void k_hist(const int* __restrict__ ei, int* __restrict__ counts) {
  int e = blockIdx.x * 256 + threadIdx.x;
  if (e < EE) atomicAdd(&counts[ei[EE + e]], 1);
}

// ---- hierarchical scan ----
__global__ __launch_bounds__(1024) void k_scan1(const int* __restrict__ counts,
                                                int* __restrict__ partial,
                                                int* __restrict__ blockSums) {
  __shared__ int tmp[1024];
  int t = threadIdx.x;
  int i = blockIdx.x * 1024 + t;
  int v = (i < NN) ? counts[i] : 0;
  tmp[t] = v;
  __syncthreads();
  for (int off = 1; off < 1024; off <<= 1) {
    int u = (t >= off) ? tmp[t - off] : 0;
    __syncthreads();
    tmp[t] += u;
    __syncthreads();
  }
  if (i < NN) partial[i] = tmp[t] - v;  // exclusive within block
  if (t == 1023) blockSums[blockIdx.x] = tmp[1023];
}

// ---- block offsets (wave-reduced) -> ptr/cursor; self-loop placed here ----
__global__ __launch_bounds__(1024) void k_scan3(const int* __restrict__ partial,
                                                const int* __restrict__ blockSums,
                                                int* __restrict__ ptr,
                                                int* __restrict__ cursor,
                                                int* __restrict__ csr) {
  __shared__ int boff;
  if (threadIdx.x < 64) {
    int v = (threadIdx.x < blockIdx.x) ? blockSums[threadIdx.x] : 0;
    v += __shfl_xor(v, 1);
    v += __shfl_xor(v, 2);
    v += __shfl_xor(v, 4);
    v += __shfl_xor(v, 8);
    v += __shfl_xor(v, 16);
    v += __shfl_xor(v, 32);
    if (threadIdx.x == 0) boff = v;
  }
  __syncthreads();
  int i = blockIdx.x * 1024 + threadIdx.x;
  if (i < NN) {
    int v = partial[i] + boff;
    ptr[i] = v;
    csr[v] = i;          // self-loop occupies first slot
    cursor[i] = v + 1;   // real edges start after it
    if (i == NN - 1) ptr[NN] = EE + NN;
  }
}

__global__ void k_scatter(const int* __restrict__ ei, int* __restrict__ cursor,
                          int* __restrict__ csr) {
  int e = blockIdx.x * 256 + threadIdx.x;
  if (e < EE) {
    int dst = ei[EE + e];
    int pos = atomicAdd(&cursor[dst], 1);
    csr[pos] = ei[e];
  }
}

// ---- per-node FLAT-softmax aggregation + epilogue ----
// leaky(t) = 0.6t + 0.4|t|  =>  logit = dl6[src] + 1.5*(att04 . xr) + sum att04_c*|xl+xr|
#define ABSDOT(ex, ey, ez, ew, p)              \
  p = av4.x * fabsf(ex + xrx);                 \
  p = fmaf(av4.y, fabsf(ey + xry), p);         \
  p = fmaf(av4.z, fabsf(ez + xrz), p);         \
  p = fmaf(av4.w, fabsf(ew + xrw), p);

__global__ __launch_bounds__(256) void k_agg(const uint2* __restrict__ xl2,
                                             const uint2* __restrict__ zb2,
                                             const float* __restrict__ dl6,
                                             const int* __restrict__ ptr,
                                             const int* __restrict__ csr,
                                             const float* __restrict__ att04,
                                             const float* __restrict__ bias,
                                             float* __restrict__ out) {
  int node = blockIdx.x * 4 + (threadIdx.x >> 6);
  if (node >= NN) return;
  int lane = threadIdx.x & 63;
  int hid = lane >> 3;

  uint2 xrv = zb2[(size_t)node * 128 + lane];
  float xrx = bfl(xrv.x), xry = bfh(xrv.x), xrz = bfl(xrv.y), xrw = bfh(xrv.y);
  const float4 av4 = *(const float4*)(att04 + lane * 4);

  // dst-side dot term, hoisted out of the edge loop
  float drp = av4.x * xrx + av4.y * xry + av4.z * xrz + av4.w * xrw;
  drp += __shfl_xor(drp, 1);
  drp += __shfl_xor(drp, 2);
  drp += __shfl_xor(drp, 4);
  float base_r = 1.5f * drp;  // = 0.6 * (att . xr)

  float sA = 0.f, axA = 0.f, ayA = 0.f, azA = 0.f, awA = 0.f;
  float sB = 0.f, axB = 0.f, ayB = 0.f, azB = 0.f, awB = 0.f;
  int beg = ptr[node], end = ptr[node + 1];
  int i = beg;
  for (; i + 4 <= end; i += 4) {
    int s0 = csr[i], s1 = csr[i + 1], s2 = csr[i + 2], s3 = csr[i + 3];
    uint2 v0 = xl2[(size_t)s0 * 64 + lane];
    uint2 v1 = xl2[(size_t)s1 * 64 + lane];
    uint2 v2 = xl2[(size_t)s2 * 64 + lane];
    uint2 v3 = xl2[(size_t)s3 * 64 + lane];
    float d0 = dl6[(size_t)s0 * 8 + hid];
    float d1 = dl6[(size_t)s1 * 8 + hid];
    float d2 = dl6[(size_t)s2 * 8 + hid];
    float d3 = dl6[(size_t)s3 * 8 + hid];
    float e0x = bfl(v0.x), e0y = bfh(v0.x), e0z = bfl(v0.y), e0w = bfh(v0.y);
    float e1x = bfl(v1.x), e1y = bfh(v1.x), e1z = bfl(v1.y), e1w = bfh(v1.y);
    float e2x = bfl(v2.x), e2y = bfh(v2.x), e2z = bfl(v2.y), e2w = bfh(v2.y);
    float e3x = bfl(v3.x), e3y = bfh(v3.x), e3z = bfl(v3.y), e3w = bfh(v3.y);
    float p0, p1, p2, p3;
    ABSDOT(e0x, e0y, e0z, e0w, p0)
    ABSDOT(e1x, e1y, e1z, e1w, p1)
    ABSDOT(e2x, e2y, e2z, e2w, p2)
    ABSDOT(e3x, e3y, e3z, e3w, p3)
    p0 += __shfl_xor(p0, 1); p1 += __shfl_xor(p1, 1);
    p2 += __shfl_xor(p2, 1); p3 += __shfl_xor(p3, 1);
    p0 += __shfl_xor(p0, 2); p1 += __shfl_xor(p1, 2);
    p2 += __shfl_xor(p2, 2); p3 += __shfl_xor(p3, 2);
    p0 += __shfl_xor(p0, 4); p1 += __shfl_xor(p1, 4);
    p2 += __shfl_xor(p2, 4); p3 += __shfl_xor(p3, 4);
    p0 = __expf(p0 + d0 + base_r); p1 = __expf(p1 + d1 + base_r);
    p2 = __expf(p2 + d2 + base_r); p3 = __expf(p3 + d3 + base_r);
    sA += p0;  axA += p0 * e0x; ayA += p0 * e0y; azA += p0 * e0z; awA += p0 * e0w;
    sB += p1;  axB += p1 * e1x; ayB += p1 * e1y; azB += p1 * e1z; awB += p1 * e1w;
    sA += p2;  axA += p2 * e2x; ayA += p2 * e2y; azA += p2 * e2z; awA += p2 * e2w;
    sB += p3;  axB += p3 * e3x; ayB += p3 * e3y; azB += p3 * e3z; awB += p3 * e3w;
  }
  for (; i < end; ++i) {
    int s0 = csr[i];
    uint2 v0 = xl2[(size_t)s0 * 64 + lane];
    float d0 = dl6[(size_t)s0 * 8 + hid];
    float e0x = bfl(v0.x), e0y = bfh(v0.x), e0z = bfl(v0.y), e0w = bfh(v0.y);
    float p0;
    ABSDOT(e0x, e0y, e0z, e0w, p0)
    p0 += __shfl_xor(p0, 1);
    p0 += __shfl_xor(p0, 2);
    p0 += __shfl_xor(p0, 4);
    p0 = __expf(p0 + d0 + base_r);
    sA += p0;  axA += p0 * e0x; ayA += p0 * e0y; azA += p0 * e0z; awA += p0 * e0w;
  }
  float inv = 1.f / (sA + sB);
  uint2 skv = zb2[(size_t)node * 128 + 64 + lane];
  const float4 bv = *(const float4*)(bias + lane * 4);
  float4 o;
  o.x = (axA + axB) * inv + bv.x; o.x = (o.x > 0.f) ? o.x : 0.01f * o.x; o.x += bfl(skv.x);
  o.y = (ayA + ayB) * inv + bv.y; o.y = (o.y > 0.f) ? o.y : 0.01f * o.y; o.y += bfh(skv.x);
  o.z = (azA + azB) * inv + bv.z; o.z = (o.z > 0.f) ? o.z : 0.01f * o.z; o.z += bfl(skv.y);
  o.w = (awA + awB) * inv + bv.w; o.w = (o.w > 0.f) ? o.w : 0.01f * o.w; o.w += bfh(skv.y);
  *(float4*)(out + (size_t)node * 256 + lane * 4) = o;
}

extern "C" void kernel_launch(void* const* d_in, const int* in_sizes, int n_in,
                              void* d_out, int out_size, void* d_ws, size_t ws_size,
                              hipStream_t stream) {
  const float* x = (const float*)d_in[0];
  const float* Wl = (const float*)d_in[1];
  const float* Wr = (const float*)d_in[2];
  const float* att = (const float*)d_in[3];
  const float* bias = (const float*)d_in[4];
  const float* Wskip = (const float*)d_in[5];
  const int* ei = (const int*)d_in[6];
  float* out = (float*)d_out;

  char* w = (char*)d_ws;
  size_t off = 0;
  auto alloc = [&](size_t bytes) {
    void* p = w + off;
    off = (off + bytes + 255) & ~(size_t)255;
    return p;
  };
  unsigned short* xb = (unsigned short*)alloc((size_t)NN * 256 * 2);
  unsigned short* wb = (unsigned short*)alloc((size_t)768 * 256 * 2);
  unsigned short* xlb = (unsigned short*)alloc((size_t)NN * 256 * 2);
  unsigned short* zb = (unsigned short*)alloc((size_t)NN * 512 * 2);
  float* dl6 = (float*)alloc((size_t)NN * 8 * 4);
  float* att04 = (float*)alloc(256 * 4);
  int* counts = (int*)alloc((size_t)NN * 4);
  int* partial = (int*)alloc((size_t)NN * 4);
  int* blockSums = (int*)alloc((size_t)SCAN_BLOCKS * 4);
  int* ptr = (int*)alloc((size_t)(NN + 1) * 4);
  int* cursor = (int*)alloc((size_t)NN * 4);
  int* csr = (int*)alloc((size_t)(EE + NN) * 4);
  if (ws_size < off) return;  // clean failure signal (out stays zero)

  k_prep<<<12889, 256, 0, stream>>>((const float4*)x, (const float4*)Wl,
                                    (const float4*)Wr, (const float4*)Wskip, att,
                                    (uint2*)xb, (uint2*)wb, counts, att04);
  k_hist<<<(EE + 255) / 256, 256, 0, stream>>>(ei, counts);
  dim3 g((NN + 127) / 128, 6);
  k_gemm<<<g, 256, 0, stream>>>(xb, wb, xlb, zb);
  k_dots<<<(NN + 3) / 4, 256, 0, stream>>>((const uint2*)xlb, att04, dl6);
  k_scan1<<<SCAN_BLOCKS, 1024, 0, stream>>>(counts, partial, blockSums);
  k_scan3<<<SCAN_BLOCKS, 1024, 0, stream>>>(partial, blockSums, ptr, cursor, csr);
  k_scatter<<<(EE + 255) / 256, 256, 0, stream>>>(ei, cursor, csr);
  k_agg<<<(NN + 3) / 4, 256, 0, stream>>>((const uint2*)xlb, (const uint2*)zb, dl6,
                                          ptr, csr, att04, bias, out);
}

// Round 6
// 227.877 us; speedup vs baseline: 1.0353x; 1.0353x over previous
//
#include <hip/hip_runtime.h>

#define NN 50000
#define EE 800000
#define SCAN_BLOCKS 49  // 49*1024 >= 50000

typedef __attribute__((ext_vector_type(4))) float f32x4;
typedef __attribute__((ext_vector_type(8))) short bf16x8;
typedef unsigned int u32;
#define GLOBAL_AS __attribute__((address_space(1)))
#define LDS_AS __attribute__((address_space(3)))

static __device__ __forceinline__ unsigned short f2bf(float f) {
  unsigned int u = __float_as_uint(f);
  u += 0x7FFFu + ((u >> 16) & 1u);
  return (unsigned short)(u >> 16);
}
static __device__ __forceinline__ float bfl(unsigned int u) { return __uint_as_float(u << 16); }
static __device__ __forceinline__ float bfh(unsigned int u) { return __uint_as_float(u & 0xFFFF0000u); }

// ---- fused prep: conv x->bf16 | conv W->bf16 | att scales ----
__global__ void k_prep(const float4* __restrict__ x4,
                       const float4* __restrict__ Wl, const float4* __restrict__ Wr,
                       const float4* __restrict__ Ws, const float* __restrict__ att,
                       uint2* __restrict__ xb2, uint2* __restrict__ wb2,
                       float* __restrict__ av6, float* __restrict__ av04) {
  int b = blockIdx.x;
  if (b < 12500) {
    int i = b * 256 + threadIdx.x;  // < 3200000 exactly
    float4 v = x4[i];
    uint2 o;
    o.x = (unsigned)f2bf(v.x) | ((unsigned)f2bf(v.y) << 16);
    o.y = (unsigned)f2bf(v.z) | ((unsigned)f2bf(v.w) << 16);
    xb2[i] = o;
  } else if (b < 12692) {
    int i = (b - 12500) * 256 + threadIdx.x;  // over 49152
    if (i < 49152) {
      int which = i >> 14;
      int idx = i & 16383;
      const float4* W = (which == 0) ? Wl : (which == 1) ? Wr : Ws;
      float4 v = W[idx];
      uint2 o;
      o.x = (unsigned)f2bf(v.x) | ((unsigned)f2bf(v.y) << 16);
      o.y = (unsigned)f2bf(v.z) | ((unsigned)f2bf(v.w) << 16);
      wb2[i] = o;
    }
  } else {
    float a = att[threadIdx.x];
    av6[threadIdx.x] = 0.6f * a;
    av04[threadIdx.x] = 0.4f * a;
  }
}

// ---- GEMM: cols 0-255 -> xlb (bf16 [N][256]), cols 256-767 -> zb (bf16 [N][512]) ----
// Staging via global_load_lds: linear LDS dest, XOR-swizzle applied to the
// GLOBAL source address (rule #21); reads use the same swizzle.
__global__ __launch_bounds__(256) void k_gemm(const unsigned short* __restrict__ xb,
                                              const unsigned short* __restrict__ wb,
                                              unsigned short* __restrict__ xlb,
                                              unsigned short* __restrict__ zb) {
  __shared__ alignas(16) unsigned short As[128 * 64];
  __shared__ alignas(16) unsigned short Bs[128 * 64];
  const int tid = threadIdx.x;
  const int lane = tid & 63;
  const int wave = tid >> 6;
  const int wr = wave >> 1, wc = wave & 1;
  const int rbase = blockIdx.x * 128;
  const int cbase = blockIdx.y * 128;
  const int rl = lane & 15;
  const int q = lane >> 4;

  f32x4 acc[4][4];
#pragma unroll
  for (int a = 0; a < 4; ++a)
#pragma unroll
    for (int b = 0; b < 4; ++b) acc[a][b] = (f32x4){0.f, 0.f, 0.f, 0.f};

  for (int kt = 0; kt < 256; kt += 64) {
#pragma unroll
    for (int i = 0; i < 4; ++i) {
      int c = tid + i * 256;            // chunk id: 1024 chunks of 16B per buffer
      int row = c >> 3, kcx = c & 7;    // kcx = physical (linear LDS) slot
      int kc = kcx ^ (row & 7);         // logical k-chunk that lives in slot kcx
      int gr = rbase + row; if (gr > NN - 1) gr = NN - 1;
      int ldsoff = i * 4096 + wave * 1024;  // wave-uniform byte base
      __builtin_amdgcn_global_load_lds(
          (const GLOBAL_AS u32*)(xb + (size_t)gr * 256 + kt + kc * 8),
          (LDS_AS u32*)((LDS_AS char*)As + ldsoff), 16, 0, 0);
      __builtin_amdgcn_global_load_lds(
          (const GLOBAL_AS u32*)(wb + (size_t)(cbase + row) * 256 + kt + kc * 8),
          (LDS_AS u32*)((LDS_AS char*)Bs + ldsoff), 16, 0, 0);
    }
    __syncthreads();
#pragma unroll
    for (int ks = 0; ks < 2; ++ks) {
      bf16x8 af[4], bf[4];
      int kc = ks * 4 + q;
#pragma unroll
      for (int t = 0; t < 4; ++t) {
        int ra = wr * 64 + t * 16 + rl;
        af[t] = *(const bf16x8*)((const char*)As + ra * 128 + ((kc << 4) ^ ((ra & 7) << 4)));
        int rb = wc * 64 + t * 16 + rl;
        bf[t] = *(const bf16x8*)((const char*)Bs + rb * 128 + ((kc << 4) ^ ((rb & 7) << 4)));
      }
#pragma unroll
      for (int a = 0; a < 4; ++a)
#pragma unroll
        for (int b = 0; b < 4; ++b)
          acc[a][b] = __builtin_amdgcn_mfma_f32_16x16x32_bf16(af[a], bf[b], acc[a][b], 0, 0, 0);
    }
    __syncthreads();
  }
  const bool isxl = (cbase < 256);
#pragma unroll
  for (int a = 0; a < 4; ++a) {
#pragma unroll
    for (int j = 0; j < 4; ++j) {
      int row = rbase + wr * 64 + a * 16 + q * 4 + j;
      if (row < NN) {
#pragma unroll
        for (int b = 0; b < 4; ++b) {
          int col = cbase + wc * 64 + b * 16 + rl;
          if (isxl)
            xlb[(size_t)row * 256 + col] = f2bf(acc[a][b][j]);
          else
            zb[(size_t)row * 512 + (col - 256)] = f2bf(acc[a][b][j]);
        }
      }
    }
  }
}

__global__ void k_hist(const int* __restrict__ ei, int* __restrict__ counts) {
  int e = blockIdx.x * 256 + threadIdx.x;
  if (e < EE) atomicAdd(&counts[ei[EE + e]], 1);
}

// ---- hierarchical scan (counts+1 folds in the self-loop) ----
__global__ __launch_bounds__(1024) void k_scan1(const int* __restrict__ counts,
                                                int* __restrict__ partial,
                                                int* __restrict__ blockSums) {
  __shared__ int tmp[1024];
  int t = threadIdx.x;
  int i = blockIdx.x * 1024 + t;
  int v = (i < NN) ? (counts[i] + 1) : 0;
  tmp[t] = v;
  __syncthreads();
  for (int off = 1; off < 1024; off <<= 1) {
    int u = (t >= off) ? tmp[t - off] : 0;
    __syncthreads();
    tmp[t] += u;
    __syncthreads();
  }
  if (i < NN) partial[i] = tmp[t] - v;  // exclusive within block
  if (t == 1023) blockSums[blockIdx.x] = tmp[1023];
}

// ---- block offsets (wave-reduced) -> ptr/cursor; self-loop placed here ----
__global__ __launch_bounds__(1024) void k_scan3(const int* __restrict__ partial,
                                                const int* __restrict__ blockSums,
                                                int* __restrict__ ptr,
                                                int* __restrict__ cursor,
                                                int* __restrict__ csr) {
  __shared__ int boff;
  if (threadIdx.x < 64) {
    int v = (threadIdx.x < blockIdx.x) ? blockSums[threadIdx.x] : 0;
    v += __shfl_xor(v, 1);
    v += __shfl_xor(v, 2);
    v += __shfl_xor(v, 4);
    v += __shfl_xor(v, 8);
    v += __shfl_xor(v, 16);
    v += __shfl_xor(v, 32);
    if (threadIdx.x == 0) boff = v;
  }
  __syncthreads();
  int i = blockIdx.x * 1024 + threadIdx.x;
  if (i < NN) {
    int v = partial[i] + boff;
    ptr[i] = v;
    csr[v] = i;          // self-loop occupies first slot
    cursor[i] = v + 1;   // real edges start after it
    if (i == NN - 1) ptr[NN] = EE + NN;
  }
}

__global__ void k_scatter(const int* __restrict__ ei, int* __restrict__ cursor,
                          int* __restrict__ csr) {
  int e = blockIdx.x * 256 + threadIdx.x;
  if (e < EE) {
    int dst = ei[EE + e];
    int pos = atomicAdd(&cursor[dst], 1);
    csr[pos] = ei[e];
  }
}

// ---- per-node FLAT-softmax aggregation + epilogue ----
// a.leaky(t) = sum (0.6a_c) t_c + (0.4a_c)|t_c| : 3 VALU/ch, abs = free modifier,
// no second gather stream (R5 post-mortem: any per-edge gather > 4 VALU).
#define LOGIT6(ex, ey, ez, ew, p)                                      \
  t = ex + xrx; p = a6.x * t;        p = fmaf(a04.x, fabsf(t), p);     \
  t = ey + xry; p = fmaf(a6.y, t, p); p = fmaf(a04.y, fabsf(t), p);    \
  t = ez + xrz; p = fmaf(a6.z, t, p); p = fmaf(a04.z, fabsf(t), p);    \
  t = ew + xrw; p = fmaf(a6.w, t, p); p = fmaf(a04.w, fabsf(t), p);

__global__ __launch_bounds__(256) void k_agg(const uint2* __restrict__ xl2,
                                             const uint2* __restrict__ zb2,
                                             const int* __restrict__ ptr,
                                             const int* __restrict__ csr,
                                             const float* __restrict__ av6,
                                             const float* __restrict__ av04,
                                             const float* __restrict__ bias,
                                             float* __restrict__ out) {
  int node = blockIdx.x * 4 + (threadIdx.x >> 6);
  if (node >= NN) return;
  int lane = threadIdx.x & 63;

  uint2 xrv = zb2[(size_t)node * 128 + lane];
  float xrx = bfl(xrv.x), xry = bfh(xrv.x), xrz = bfl(xrv.y), xrw = bfh(xrv.y);
  const float4 a6 = *(const float4*)(av6 + lane * 4);
  const float4 a04 = *(const float4*)(av04 + lane * 4);

  float sA = 0.f, axA = 0.f, ayA = 0.f, azA = 0.f, awA = 0.f;
  float sB = 0.f, axB = 0.f, ayB = 0.f, azB = 0.f, awB = 0.f;
  int beg = ptr[node], end = ptr[node + 1];
  int i = beg;
  for (; i + 4 <= end; i += 4) {
    int s0 = csr[i], s1 = csr[i + 1], s2 = csr[i + 2], s3 = csr[i + 3];
    uint2 v0 = xl2[(size_t)s0 * 64 + lane];
    uint2 v1 = xl2[(size_t)s1 * 64 + lane];
    uint2 v2 = xl2[(size_t)s2 * 64 + lane];
    uint2 v3 = xl2[(size_t)s3 * 64 + lane];
    float e0x = bfl(v0.x), e0y = bfh(v0.x), e0z = bfl(v0.y), e0w = bfh(v0.y);
    float e1x = bfl(v1.x), e1y = bfh(v1.x), e1z = bfl(v1.y), e1w = bfh(v1.y);
    float e2x = bfl(v2.x), e2y = bfh(v2.x), e2z = bfl(v2.y), e2w = bfh(v2.y);
    float e3x = bfl(v3.x), e3y = bfh(v3.x), e3z = bfl(v3.y), e3w = bfh(v3.y);
    float t, p0, p1, p2, p3;
    LOGIT6(e0x, e0y, e0z, e0w, p0)
    LOGIT6(e1x, e1y, e1z, e1w, p1)
    LOGIT6(e2x, e2y, e2z, e2w, p2)
    LOGIT6(e3x, e3y, e3z, e3w, p3)
    p0 += __shfl_xor(p0, 1); p1 += __shfl_xor(p1, 1);
    p2 += __shfl_xor(p2, 1); p3 += __shfl_xor(p3, 1);
    p0 += __shfl_xor(p0, 2); p1 += __shfl_xor(p1, 2);
    p2 += __shfl_xor(p2, 2); p3 += __shfl_xor(p3, 2);
    p0 += __shfl_xor(p0, 4); p1 += __shfl_xor(p1, 4);
    p2 += __shfl_xor(p2, 4); p3 += __shfl_xor(p3, 4);
    p0 = __expf(p0); p1 = __expf(p1); p2 = __expf(p2); p3 = __expf(p3);
    sA += p0;  axA += p0 * e0x; ayA += p0 * e0y; azA += p0 * e0z; awA += p0 * e0w;
    sB += p1;  axB += p1 * e1x; ayB += p1 * e1y; azB += p1 * e1z; awB += p1 * e1w;
    sA += p2;  axA += p2 * e2x; ayA += p2 * e2y; azA += p2 * e2z; awA += p2 * e2w;
    sB += p3;  axB += p3 * e3x; ayB += p3 * e3y; azB += p3 * e3z; awB += p3 * e3w;
  }
  for (; i < end; ++i) {
    int s0 = csr[i];
    uint2 v0 = xl2[(size_t)s0 * 64 + lane];
    float e0x = bfl(v0.x), e0y = bfh(v0.x), e0z = bfl(v0.y), e0w = bfh(v0.y);
    float t, p0;
    LOGIT6(e0x, e0y, e0z, e0w, p0)
    p0 += __shfl_xor(p0, 1);
    p0 += __shfl_xor(p0, 2);
    p0 += __shfl_xor(p0, 4);
    p0 = __expf(p0);
    sA += p0;  axA += p0 * e0x; ayA += p0 * e0y; azA += p0 * e0z; awA += p0 * e0w;
  }
  float inv = 1.f / (sA + sB);
  uint2 skv = zb2[(size_t)node * 128 + 64 + lane];
  const float4 bv = *(const float4*)(bias + lane * 4);
  float4 o;
  o.x = (axA + axB) * inv + bv.x; o.x = (o.x > 0.f) ? o.x : 0.01f * o.x; o.x += bfl(skv.x);
  o.y = (ayA + ayB) * inv + bv.y; o.y = (o.y > 0.f) ? o.y : 0.01f * o.y; o.y += bfh(skv.x);
  o.z = (azA + azB) * inv + bv.z; o.z = (o.z > 0.f) ? o.z : 0.01f * o.z; o.z += bfl(skv.y);
  o.w = (awA + awB) * inv + bv.w; o.w = (o.w > 0.f) ? o.w : 0.01f * o.w; o.w += bfh(skv.y);
  *(float4*)(out + (size_t)node * 256 + lane * 4) = o;
}

extern "C" void kernel_launch(void* const* d_in, const int* in_sizes, int n_in,
                              void* d_out, int out_size, void* d_ws, size_t ws_size,
                              hipStream_t stream) {
  const float* x = (const float*)d_in[0];
  const float* Wl = (const float*)d_in[1];
  const float* Wr = (const float*)d_in[2];
  const float* att = (const float*)d_in[3];
  const float* bias = (const float*)d_in[4];
  const float* Wskip = (const float*)d_in[5];
  const int* ei = (const int*)d_in[6];
  float* out = (float*)d_out;

  char* w = (char*)d_ws;
  size_t off = 0;
  auto alloc = [&](size_t bytes) {
    void* p = w + off;
    off = (off + bytes + 255) & ~(size_t)255;
    return p;
  };
  unsigned short* xb = (unsigned short*)alloc((size_t)NN * 256 * 2);
  unsigned short* wb = (unsigned short*)alloc((size_t)768 * 256 * 2);
  unsigned short* xlb = (unsigned short*)alloc((size_t)NN * 256 * 2);
  unsigned short* zb = (unsigned short*)alloc((size_t)NN * 512 * 2);
  float* av6 = (float*)alloc(256 * 4);
  float* av04 = (float*)alloc(256 * 4);
  int* counts = (int*)alloc((size_t)NN * 4);
  int* partial = (int*)alloc((size_t)NN * 4);
  int* blockSums = (int*)alloc((size_t)SCAN_BLOCKS * 4);
  int* ptr = (int*)alloc((size_t)(NN + 1) * 4);
  int* cursor = (int*)alloc((size_t)NN * 4);
  int* csr = (int*)alloc((size_t)(EE + NN) * 4);
  if (ws_size < off) return;  // clean failure signal (out stays zero)

  hipMemsetAsync(counts, 0, (size_t)NN * 4, stream);
  k_prep<<<12693, 256, 0, stream>>>((const float4*)x, (const float4*)Wl,
                                    (const float4*)Wr, (const float4*)Wskip, att,
                                    (uint2*)xb, (uint2*)wb, av6, av04);
  k_hist<<<(EE + 255) / 256, 256, 0, stream>>>(ei, counts);
  dim3 g((NN + 127) / 128, 6);
  k_gemm<<<g, 256, 0, stream>>>(xb, wb, xlb, zb);
  k_scan1<<<SCAN_BLOCKS, 1024, 0, stream>>>(counts, partial, blockSums);
  k_scan3<<<SCAN_BLOCKS, 1024, 0, stream>>>(partial, blockSums, ptr, cursor, csr);
  k_scatter<<<(EE + 255) / 256, 256, 0, stream>>>(ei, cursor, csr);
  k_agg<<<(NN + 3) / 4, 256, 0, stream>>>((const uint2*)xlb, (const uint2*)zb,
                                          ptr, csr, av6, av04, bias, out);
}

// Round 7
// 227.201 us; speedup vs baseline: 1.0384x; 1.0030x over previous
//
#include <hip/hip_runtime.h>

#define NN 50000
#define EE 800000
#define SCAN_BLOCKS 49  // 49*1024 >= 50000
#define LOG2E 1.44269504088896340736f

typedef __attribute__((ext_vector_type(4))) float f32x4;
typedef __attribute__((ext_vector_type(8))) short bf16x8;
typedef unsigned int u32;
#define GLOBAL_AS __attribute__((address_space(1)))
#define LDS_AS __attribute__((address_space(3)))

static __device__ __forceinline__ u32 cvtpk_bf16(float lo, float hi) {
  u32 r;
  asm("v_cvt_pk_bf16_f32 %0, %1, %2" : "=v"(r) : "v"(lo), "v"(hi));
  return r;
}
static __device__ __forceinline__ unsigned short f2bf_hw(float f) {
  return (unsigned short)cvtpk_bf16(f, 0.f);
}
static __device__ __forceinline__ float bfl(unsigned int u) { return __uint_as_float(u << 16); }
static __device__ __forceinline__ float bfh(unsigned int u) { return __uint_as_float(u & 0xFFFF0000u); }

// ---- fused prep: conv x->bf16 | conv W->bf16 | att scales (log2e-folded) ----
__global__ void k_prep(const float4* __restrict__ x4,
                       const float4* __restrict__ Wl, const float4* __restrict__ Wr,
                       const float4* __restrict__ Ws, const float* __restrict__ att,
                       uint2* __restrict__ xb2, uint2* __restrict__ wb2,
                       float* __restrict__ av6, float* __restrict__ av04) {
  int b = blockIdx.x;
  if (b < 12500) {
    int i = b * 256 + threadIdx.x;  // < 3200000 exactly
    float4 v = x4[i];
    uint2 o;
    o.x = cvtpk_bf16(v.x, v.y);
    o.y = cvtpk_bf16(v.z, v.w);
    xb2[i] = o;
  } else if (b < 12692) {
    int i = (b - 12500) * 256 + threadIdx.x;  // over 49152
    if (i < 49152) {
      int which = i >> 14;
      int idx = i & 16383;
      const float4* W = (which == 0) ? Wl : (which == 1) ? Wr : Ws;
      float4 v = W[idx];
      uint2 o;
      o.x = cvtpk_bf16(v.x, v.y);
      o.y = cvtpk_bf16(v.z, v.w);
      wb2[i] = o;
    }
  } else {
    float a = att[threadIdx.x];
    av6[threadIdx.x] = 0.6f * LOG2E * a;
    av04[threadIdx.x] = 0.4f * LOG2E * a;
  }
}

// ---- GEMM: cols 0-255 -> xlb (bf16 [N][256]), cols 256-767 -> zb (bf16 [N][512]) ----
// Grid is (col, row) so 6 consecutive blocks share one A-tile (L3 reuse).
__global__ __launch_bounds__(256) void k_gemm(const unsigned short* __restrict__ xb,
                                              const unsigned short* __restrict__ wb,
                                              unsigned short* __restrict__ xlb,
                                              unsigned short* __restrict__ zb) {
  __shared__ alignas(16) unsigned short As[128 * 64];
  __shared__ alignas(16) unsigned short Bs[128 * 64];
  const int tid = threadIdx.x;
  const int lane = tid & 63;
  const int wave = tid >> 6;
  const int wr = wave >> 1, wc = wave & 1;
  const int rbase = blockIdx.y * 128;
  const int cbase = blockIdx.x * 128;
  const int rl = lane & 15;
  const int q = lane >> 4;

  f32x4 acc[4][4];
#pragma unroll
  for (int a = 0; a < 4; ++a)
#pragma unroll
    for (int b = 0; b < 4; ++b) acc[a][b] = (f32x4){0.f, 0.f, 0.f, 0.f};

  for (int kt = 0; kt < 256; kt += 64) {
#pragma unroll
    for (int i = 0; i < 4; ++i) {
      int c = tid + i * 256;            // chunk id: 1024 chunks of 16B per buffer
      int row = c >> 3, kcx = c & 7;    // kcx = physical (linear LDS) slot
      int kc = kcx ^ (row & 7);         // logical k-chunk that lives in slot kcx
      int gr = rbase + row; if (gr > NN - 1) gr = NN - 1;
      int ldsoff = i * 4096 + wave * 1024;  // wave-uniform byte base
      __builtin_amdgcn_global_load_lds(
          (const GLOBAL_AS u32*)(xb + (size_t)gr * 256 + kt + kc * 8),
          (LDS_AS u32*)((LDS_AS char*)As + ldsoff), 16, 0, 0);
      __builtin_amdgcn_global_load_lds(
          (const GLOBAL_AS u32*)(wb + (size_t)(cbase + row) * 256 + kt + kc * 8),
          (LDS_AS u32*)((LDS_AS char*)Bs + ldsoff), 16, 0, 0);
    }
    __syncthreads();
#pragma unroll
    for (int ks = 0; ks < 2; ++ks) {
      bf16x8 af[4], bf[4];
      int kc = ks * 4 + q;
#pragma unroll
      for (int t = 0; t < 4; ++t) {
        int ra = wr * 64 + t * 16 + rl;
        af[t] = *(const bf16x8*)((const char*)As + ra * 128 + ((kc << 4) ^ ((ra & 7) << 4)));
        int rb = wc * 64 + t * 16 + rl;
        bf[t] = *(const bf16x8*)((const char*)Bs + rb * 128 + ((kc << 4) ^ ((rb & 7) << 4)));
      }
#pragma unroll
      for (int a = 0; a < 4; ++a)
#pragma unroll
        for (int b = 0; b < 4; ++b)
          acc[a][b] = __builtin_amdgcn_mfma_f32_16x16x32_bf16(af[a], bf[b], acc[a][b], 0, 0, 0);
    }
    __syncthreads();
  }
  const bool isxl = (cbase < 256);
#pragma unroll
  for (int a = 0; a < 4; ++a) {
#pragma unroll
    for (int j = 0; j < 4; ++j) {
      int row = rbase + wr * 64 + a * 16 + q * 4 + j;
      if (row < NN) {
#pragma unroll
        for (int b = 0; b < 4; ++b) {
          int col = cbase + wc * 64 + b * 16 + rl;
          if (isxl)
            xlb[(size_t)row * 256 + col] = f2bf_hw(acc[a][b][j]);
          else
            zb[(size_t)row * 512 + (col - 256)] = f2bf_hw(acc[a][b][j]);
        }
      }
    }
  }
}

__global__ void k_hist(const int* __restrict__ ei, int* __restrict__ counts) {
  int e = blockIdx.x * 256 + threadIdx.x;
  if (e < EE) atomicAdd(&counts[ei[EE + e]], 1);
}

// ---- hierarchical scan (counts+1 folds in the self-loop) ----
__global__ __launch_bounds__(1024) void k_scan1(const int* __restrict__ counts,
                                                int* __restrict__ partial,
                                                int* __restrict__ blockSums) {
  __shared__ int tmp[1024];
  int t = threadIdx.x;
  int i = blockIdx.x * 1024 + t;
  int v = (i < NN) ? (counts[i] + 1) : 0;
  tmp[t] = v;
  __syncthreads();
  for (int off = 1; off < 1024; off <<= 1) {
    int u = (t >= off) ? tmp[t - off] : 0;
    __syncthreads();
    tmp[t] += u;
    __syncthreads();
  }
  if (i < NN) partial[i] = tmp[t] - v;  // exclusive within block
  if (t == 1023) blockSums[blockIdx.x] = tmp[1023];
}

// ---- block offsets (wave-reduced) -> ptr/cursor; self-loop placed here ----
__global__ __launch_bounds__(1024) void k_scan3(const int* __restrict__ partial,
                                                const int* __restrict__ blockSums,
                                                int* __restrict__ ptr,
                                                int* __restrict__ cursor,
                                                int* __restrict__ csr) {
  __shared__ int boff;
  if (threadIdx.x < 64) {
    int v = (threadIdx.x < blockIdx.x) ? blockSums[threadIdx.x] : 0;
    v += __shfl_xor(v, 1);
    v += __shfl_xor(v, 2);
    v += __shfl_xor(v, 4);
    v += __shfl_xor(v, 8);
    v += __shfl_xor(v, 16);
    v += __shfl_xor(v, 32);
    if (threadIdx.x == 0) boff = v;
  }
  __syncthreads();
  int i = blockIdx.x * 1024 + threadIdx.x;
  if (i < NN) {
    int v = partial[i] + boff;
    ptr[i] = v;
    csr[v] = i;          // self-loop occupies first slot
    cursor[i] = v + 1;   // real edges start after it
    if (i == NN - 1) ptr[NN] = EE + NN;
  }
}

__global__ void k_scatter(const int* __restrict__ ei, int* __restrict__ cursor,
                          int* __restrict__ csr) {
  int e = blockIdx.x * 256 + threadIdx.x;
  if (e < EE) {
    int dst = ei[EE + e];
    int pos = atomicAdd(&cursor[dst], 1);
    csr[pos] = ei[e];
  }
}

// ---- per-node FLAT-softmax aggregation + epilogue ----
// logit(log2-domain) = sum (0.6*log2e*a_c) t_c + (0.4*log2e*a_c)|t_c|; exp2f = 1 v_exp.
#define LOGIT6(ex, ey, ez, ew, p)                                      \
  t = ex + xrx; p = a6.x * t;         p = fmaf(a04.x, fabsf(t), p);    \
  t = ey + xry; p = fmaf(a6.y, t, p); p = fmaf(a04.y, fabsf(t), p);    \
  t = ez + xrz; p = fmaf(a6.z, t, p); p = fmaf(a04.z, fabsf(t), p);    \
  t = ew + xrw; p = fmaf(a6.w, t, p); p = fmaf(a04.w, fabsf(t), p);

__global__ __launch_bounds__(256) void k_agg(const uint2* __restrict__ xl2,
                                             const uint2* __restrict__ zb2,
                                             const int* __restrict__ ptr,
                                             const int* __restrict__ csr,
                                             const float* __restrict__ av6,
                                             const float* __restrict__ av04,
                                             const float* __restrict__ bias,
                                             float* __restrict__ out) {
  int node = blockIdx.x * 4 + (threadIdx.x >> 6);
  if (node >= NN) return;
  int lane = threadIdx.x & 63;

  uint2 xrv = zb2[(size_t)node * 128 + lane];
  float xrx = bfl(xrv.x), xry = bfh(xrv.x), xrz = bfl(xrv.y), xrw = bfh(xrv.y);
  const float4 a6 = *(const float4*)(av6 + lane * 4);
  const float4 a04 = *(const float4*)(av04 + lane * 4);

  float sA = 0.f, axA = 0.f, ayA = 0.f, azA = 0.f, awA = 0.f;
  float sB = 0.f, axB = 0.f, ayB = 0.f, azB = 0.f, awB = 0.f;
  int beg = ptr[node], end = ptr[node + 1];
  int i = beg;
  // 8-deep: all gathers issued up front (MLP), fully unrolled => static indices.
  for (; i + 8 <= end; i += 8) {
    int sidx[8];
    uint2 vv[8];
    float e[8][4], pp[8];
#pragma unroll
    for (int u = 0; u < 8; ++u) sidx[u] = csr[i + u];
#pragma unroll
    for (int u = 0; u < 8; ++u) vv[u] = xl2[(size_t)sidx[u] * 64 + lane];
#pragma unroll
    for (int u = 0; u < 8; ++u) {
      e[u][0] = bfl(vv[u].x); e[u][1] = bfh(vv[u].x);
      e[u][2] = bfl(vv[u].y); e[u][3] = bfh(vv[u].y);
      float t, p;
      LOGIT6(e[u][0], e[u][1], e[u][2], e[u][3], p)
      pp[u] = p;
    }
#pragma unroll
    for (int u = 0; u < 8; ++u) pp[u] += __shfl_xor(pp[u], 1);
#pragma unroll
    for (int u = 0; u < 8; ++u) pp[u] += __shfl_xor(pp[u], 2);
#pragma unroll
    for (int u = 0; u < 8; ++u) pp[u] += __shfl_xor(pp[u], 4);
#pragma unroll
    for (int u = 0; u < 8; ++u) pp[u] = exp2f(pp[u]);
#pragma unroll
    for (int u = 0; u < 8; ++u) {
      float p = pp[u];
      if (u & 1) {
        sB += p; axB = fmaf(p, e[u][0], axB); ayB = fmaf(p, e[u][1], ayB);
        azB = fmaf(p, e[u][2], azB); awB = fmaf(p, e[u][3], awB);
      } else {
        sA += p; axA = fmaf(p, e[u][0], axA); ayA = fmaf(p, e[u][1], ayA);
        azA = fmaf(p, e[u][2], azA); awA = fmaf(p, e[u][3], awA);
      }
    }
  }
  for (; i + 2 <= end; i += 2) {
    int s0 = csr[i], s1 = csr[i + 1];
    uint2 v0 = xl2[(size_t)s0 * 64 + lane];
    uint2 v1 = xl2[(size_t)s1 * 64 + lane];
    float e0x = bfl(v0.x), e0y = bfh(v0.x), e0z = bfl(v0.y), e0w = bfh(v0.y);
    float e1x = bfl(v1.x), e1y = bfh(v1.x), e1z = bfl(v1.y), e1w = bfh(v1.y);
    float t, p0, p1;
    LOGIT6(e0x, e0y, e0z, e0w, p0)
    LOGIT6(e1x, e1y, e1z, e1w, p1)
    p0 += __shfl_xor(p0, 1); p1 += __shfl_xor(p1, 1);
    p0 += __shfl_xor(p0, 2); p1 += __shfl_xor(p1, 2);
    p0 += __shfl_xor(p0, 4); p1 += __shfl_xor(p1, 4);
    p0 = exp2f(p0); p1 = exp2f(p1);
    sA += p0;  axA += p0 * e0x; ayA += p0 * e0y; azA += p0 * e0z; awA += p0 * e0w;
    sB += p1;  axB += p1 * e1x; ayB += p1 * e1y; azB += p1 * e1z; awB += p1 * e1w;
  }
  if (i < end) {
    int s0 = csr[i];
    uint2 v0 = xl2[(size_t)s0 * 64 + lane];
    float e0x = bfl(v0.x), e0y = bfh(v0.x), e0z = bfl(v0.y), e0w = bfh(v0.y);
    float t, p0;
    LOGIT6(e0x, e0y, e0z, e0w, p0)
    p0 += __shfl_xor(p0, 1);
    p0 += __shfl_xor(p0, 2);
    p0 += __shfl_xor(p0, 4);
    p0 = exp2f(p0);
    sA += p0;  axA += p0 * e0x; ayA += p0 * e0y; azA += p0 * e0z; awA += p0 * e0w;
  }
  float inv = 1.f / (sA + sB);
  uint2 skv = zb2[(size_t)node * 128 + 64 + lane];
  const float4 bv = *(const float4*)(bias + lane * 4);
  float4 o;
  o.x = (axA + axB) * inv + bv.x; o.x = (o.x > 0.f) ? o.x : 0.01f * o.x; o.x += bfl(skv.x);
  o.y = (ayA + ayB) * inv + bv.y; o.y = (o.y > 0.f) ? o.y : 0.01f * o.y; o.y += bfh(skv.x);
  o.z = (azA + azB) * inv + bv.z; o.z = (o.z > 0.f) ? o.z : 0.01f * o.z; o.z += bfl(skv.y);
  o.w = (awA + awB) * inv + bv.w; o.w = (o.w > 0.f) ? o.w : 0.01f * o.w; o.w += bfh(skv.y);
  *(float4*)(out + (size_t)node * 256 + lane * 4) = o;
}

extern "C" void kernel_launch(void* const* d_in, const int* in_sizes, int n_in,
                              void* d_out, int out_size, void* d_ws, size_t ws_size,
                              hipStream_t stream) {
  const float* x = (const float*)d_in[0];
  const float* Wl = (const float*)d_in[1];
  const float* Wr = (const float*)d_in[2];
  const float* att = (const float*)d_in[3];
  const float* bias = (const float*)d_in[4];
  const float* Wskip = (const float*)d_in[5];
  const int* ei = (const int*)d_in[6];
  float* out = (float*)d_out;

  char* w = (char*)d_ws;
  size_t off = 0;
  auto alloc = [&](size_t bytes) {
    void* p = w + off;
    off = (off + bytes + 255) & ~(size_t)255;
    return p;
  };
  unsigned short* xb = (unsigned short*)alloc((size_t)NN * 256 * 2);
  unsigned short* wb = (unsigned short*)alloc((size_t)768 * 256 * 2);
  unsigned short* xlb = (unsigned short*)alloc((size_t)NN * 256 * 2);
  unsigned short* zb = (unsigned short*)alloc((size_t)NN * 512 * 2);
  float* av6 = (float*)alloc(256 * 4);
  float* av04 = (float*)alloc(256 * 4);
  int* counts = (int*)alloc((size_t)NN * 4);
  int* partial = (int*)alloc((size_t)NN * 4);
  int* blockSums = (int*)alloc((size_t)SCAN_BLOCKS * 4);
  int* ptr = (int*)alloc((size_t)(NN + 1) * 4);
  int* cursor = (int*)alloc((size_t)NN * 4);
  int* csr = (int*)alloc((size_t)(EE + NN) * 4);
  if (ws_size < off) return;  // clean failure signal (out stays zero)

  hipMemsetAsync(counts, 0, (size_t)NN * 4, stream);
  k_prep<<<12693, 256, 0, stream>>>((const float4*)x, (const float4*)Wl,
                                    (const float4*)Wr, (const float4*)Wskip, att,
                                    (uint2*)xb, (uint2*)wb, av6, av04);
  k_hist<<<(EE + 255) / 256, 256, 0, stream>>>(ei, counts);
  dim3 g(6, (NN + 127) / 128);
  k_gemm<<<g, 256, 0, stream>>>(xb, wb, xlb, zb);
  k_scan1<<<SCAN_BLOCKS, 1024, 0, stream>>>(counts, partial, blockSums);
  k_scan3<<<SCAN_BLOCKS, 1024, 0, stream>>>(partial, blockSums, ptr, cursor, csr);
  k_scatter<<<(EE + 255) / 256, 256, 0, stream>>>(ei, cursor, csr);
  k_agg<<<(NN + 3) / 4, 256, 0, stream>>>((const uint2*)xlb, (const uint2*)zb,
                                          ptr, csr, av6, av04, bias, out);
}